// Round 4
// baseline (1065.748 us; speedup 1.0000x reference)
//
#include <hip/hip_runtime.h>

#define HC   128   // H*C
#define FE   16    // edge feature dim
#define NEG  0.2f

static __device__ __forceinline__ size_t szt(int a) { return (size_t)a; }

// ---------------- CSR build (real edges only; self-loops handled in epilogue) ----------------

__global__ void k_count(const int* __restrict__ dst, int* __restrict__ cnt, int E) {
    int e = blockIdx.x * 256 + threadIdx.x;
    if (e < E) atomicAdd(&cnt[dst[e]], 1);
}

// ---- 3-phase scan: phase 1 = per-block (4096 elems) local exclusive scan ----
__global__ __launch_bounds__(1024) void k_scan1(const int* __restrict__ cnt,
                                                int* __restrict__ excl,   // = row_off (local excl)
                                                int* __restrict__ bsum, int n) {
    __shared__ int wsum[16];
    int t = threadIdx.x, lane = t & 63, wv = t >> 6;
    int i = blockIdx.x * 4096 + t * 4;
    int4 c = make_int4(0, 0, 0, 0);
    if (i + 3 < n) c = *reinterpret_cast<const int4*>(&cnt[i]);
    else if (i < n) {
        c.x = cnt[i];
        c.y = (i + 1 < n) ? cnt[i + 1] : 0;
        c.z = (i + 2 < n) ? cnt[i + 2] : 0;
    }
    int tot = c.x + c.y + c.z + c.w;
    int s = tot;
    #pragma unroll
    for (int d = 1; d < 64; d <<= 1) { int u = __shfl_up(s, d); if (lane >= d) s += u; }
    if (lane == 63) wsum[wv] = s;
    __syncthreads();
    if (t < 16) {
        int ws = wsum[t];
        #pragma unroll
        for (int d = 1; d < 16; d <<= 1) { int u = __shfl_up(ws, d); if (t >= d) ws += u; }
        wsum[t] = ws;
    }
    __syncthreads();
    int excl_t = (wv ? wsum[wv - 1] : 0) + (s - tot);
    if (i < n) {
        int4 ro;
        ro.x = excl_t;
        ro.y = ro.x + c.x;
        ro.z = ro.y + c.y;
        ro.w = ro.z + c.z;
        if (i + 3 < n) *reinterpret_cast<int4*>(&excl[i]) = ro;
        else {
            excl[i] = ro.x;
            if (i + 1 < n) excl[i + 1] = ro.y;
            if (i + 2 < n) excl[i + 2] = ro.z;
        }
    }
    if (t == 0) bsum[blockIdx.x] = wsum[15];
}

// phase 2: single-wave scan of block sums (exclusive, in place)
__global__ void k_scan2(int* __restrict__ bsum, int nb) {
    int t = threadIdx.x;   // 64 threads
    int carry = 0;
    for (int base = 0; base < nb; base += 64) {
        int i = base + t;
        int v = (i < nb) ? bsum[i] : 0;
        int s = v;
        #pragma unroll
        for (int d = 1; d < 64; d <<= 1) { int u = __shfl_up(s, d); if (t >= d) s += u; }
        if (i < nb) bsum[i] = carry + s - v;
        carry += __shfl(s, 63);
    }
}

// phase 3: add block offsets, seed cursor, write row_off[n]
__global__ void k_scan3(const int* __restrict__ bsum, int* __restrict__ row_off,
                        int* __restrict__ cursor, int n, int E) {
    int i = blockIdx.x * 256 + threadIdx.x;
    if (i < n) {
        int v = row_off[i] + bsum[i >> 12];
        row_off[i] = v;
        cursor[i] = v;
    }
    if (i == n) row_off[n] = E;
}

// fill: scatter (src,eid) pair AND edge_attr row into CSR order
__global__ void k_fill(const int* __restrict__ src, const int* __restrict__ dst,
                       const float4* __restrict__ ea_in,
                       int* __restrict__ cursor, int2* __restrict__ pairs,
                       float4* __restrict__ ea_csr, int E) {
    int e = blockIdx.x * 256 + threadIdx.x;
    if (e < E) {
        int pos = atomicAdd(&cursor[dst[e]], 1);
        pairs[pos] = make_int2(src[e], e);
        float4 a = ea_in[szt(e) * 4 + 0];
        float4 b = ea_in[szt(e) * 4 + 1];
        float4 c = ea_in[szt(e) * 4 + 2];
        float4 d = ea_in[szt(e) * 4 + 3];
        ea_csr[szt(pos) * 4 + 0] = a;
        ea_csr[szt(pos) * 4 + 1] = b;
        ea_csr[szt(pos) * 4 + 2] = c;
        ea_csr[szt(pos) * 4 + 3] = d;
    }
}

// ---------------- fused projection GEMM: xl = x@Wl, xr = x@Wr ----------------

__global__ __launch_bounds__(256) void k_gemm(const float* __restrict__ x,
                                              const float* __restrict__ Wl,
                                              const float* __restrict__ Wr,
                                              float* __restrict__ xl,
                                              float* __restrict__ xr, int n) {
    __shared__ float xs[32][HC];
    int t = threadIdx.x;
    int base = blockIdx.x * 32;
    int rmax = n - base; if (rmax > 32) rmax = 32;
    for (int idx = t; idx < 32 * HC; idx += 256) {
        int r = idx >> 7, k = idx & 127;
        xs[r][k] = (r < rmax) ? x[szt(base + r) * HC + k] : 0.f;
    }
    __syncthreads();
    const float* W = (t & 128) ? Wr : Wl;
    float*       O = (t & 128) ? xr : xl;
    int c = t & 127;
    float acc[32];
    #pragma unroll
    for (int r = 0; r < 32; ++r) acc[r] = 0.f;
    for (int k = 0; k < HC; k += 4) {
        float w0 = W[(k + 0) * HC + c];
        float w1 = W[(k + 1) * HC + c];
        float w2 = W[(k + 2) * HC + c];
        float w3 = W[(k + 3) * HC + c];
        #pragma unroll
        for (int r = 0; r < 32; ++r) {
            float4 xv = *reinterpret_cast<const float4*>(&xs[r][k]);
            acc[r] += xv.x * w0 + xv.y * w1 + xv.z * w2 + xv.w * w3;
        }
    }
    #pragma unroll
    for (int r = 0; r < 32; ++r)
        if (r < rmax) O[szt(base + r) * HC + c] = acc[r];
}

// ---------------- fused per-node attention + aggregation ----------------
// 1 wave per node; lane owns channels (2*lane, 2*lane+1); head = lane/16.
// 4-edge batches: pairs (lane&3 slots) + CSR-contiguous ea (lane -> edge lane>>4,
// feature lane&15 -> float per lane, fully coalesced, independent of pairs).
// ee via k-outer loop: 1 ds_read_b64 + 4 readlane + 8 FMA per k. We in LDS.
// 1-deep prefetch of pairs/ea; xv gathers issued before ee compute.

__global__ __launch_bounds__(256) void k_fused(
    const float* __restrict__ xl, const float* __restrict__ xr,
    const float* __restrict__ ea_csr,
    const int2* __restrict__ pairs, const int* __restrict__ row_off,
    const float* __restrict__ We, const float* __restrict__ att,
    const float* __restrict__ bias,
    float* __restrict__ out, float* __restrict__ alpha,
    float* __restrict__ denom_out, int n, int E)
{
    __shared__ float sWe[FE * HC];
    for (int i = threadIdx.x; i < FE * HC; i += 256) sWe[i] = We[i];
    __syncthreads();

    int lane = threadIdx.x & 63, wv = threadIdx.x >> 6;
    int node = blockIdx.x * 4 + wv;
    if (node >= n) return;
    int c0 = lane * 2, h = lane >> 4;
    float2 attv = *reinterpret_cast<const float2*>(&att[c0]);
    float2 xrv  = *reinterpret_cast<const float2*>(&xr[szt(node) * HC + c0]);
    int beg = row_off[node], end = row_off[node + 1];
    float acc0 = 0.f, acc1 = 0.f, den = 0.f, es0 = 0.f, es1 = 0.f;

    if (beg < end) {
        int last = end - 1;
        auto ldpair = [&](int p) -> int2 {
            int idx = p + (lane & 3); if (idx > last) idx = last;
            return pairs[idx];
        };
        auto ldea = [&](int p) -> float {
            int idx = p + (lane >> 4); if (idx > last) idx = last;
            return ea_csr[szt(idx) * FE + (lane & 15)];
        };
        int2  prC = ldpair(beg);
        float eaC = ldea(beg);
        for (int p = beg; p < end; p += 4) {
            // xl-row gathers for this batch (pairs available from prefetch)
            float2 xv[4];
            #pragma unroll
            for (int j = 0; j < 4; ++j) {
                int s = __builtin_amdgcn_readlane(prC.x, j);
                xv[j] = *reinterpret_cast<const float2*>(xl + szt(s) * HC + c0);
            }
            // prefetch next batch descriptors
            int2 prN = prC; float eaN = eaC;
            if (p + 4 < end) { prN = ldpair(p + 4); eaN = ldea(p + 4); }
            int m = end - p; if (m > 4) m = 4;

            // ee for 4 edges, k-outer: w loaded once per k, broadcast ea via readlane
            float ee0[4], ee1[4];
            #pragma unroll
            for (int j = 0; j < 4; ++j) { ee0[j] = 0.f; ee1[j] = 0.f; }
            #pragma unroll
            for (int k = 0; k < FE; ++k) {
                float2 w = *reinterpret_cast<const float2*>(&sWe[k * HC + c0]);
                #pragma unroll
                for (int j = 0; j < 4; ++j) {
                    float a = __shfl(eaC, j * 16 + k);
                    ee0[j] += a * w.x;
                    ee1[j] += a * w.y;
                }
            }
            #pragma unroll
            for (int j = 0; j < 4; ++j) {
                if (j >= m) break;
                es0 += ee0[j]; es1 += ee1[j];
                float t0 = xv[j].x + xrv.x + ee0[j];
                float t1 = xv[j].y + xrv.y + ee1[j];
                t0 = t0 > 0.f ? t0 : NEG * t0;
                t1 = t1 > 0.f ? t1 : NEG * t1;
                float part = attv.x * t0 + attv.y * t1;
                part += __shfl_xor(part, 1);
                part += __shfl_xor(part, 2);
                part += __shfl_xor(part, 4);
                part += __shfl_xor(part, 8);
                float ex = __expf(part);   // logits are small: no max-subtraction needed
                den  += ex;
                acc0 += ex * xv[j].x;
                acc1 += ex * xv[j].y;
                if ((lane & 15) == 0) {
                    int e = __builtin_amdgcn_readlane(prC.y, j);
                    alpha[szt(e) * 4 + h] = ex;
                }
            }
            prC = prN; eaC = eaN;
        }
    }

    // self-loop: ee_self = mean over incoming edges of ee (0 if none)
    int deg = end - beg;
    float invd = (deg > 0) ? 1.f / (float)deg : 0.f;
    float e0 = es0 * invd, e1 = es1 * invd;
    float2 vs = *reinterpret_cast<const float2*>(&xl[szt(node) * HC + c0]);
    float t0 = vs.x + xrv.x + e0;
    float t1 = vs.y + xrv.y + e1;
    t0 = t0 > 0.f ? t0 : NEG * t0;
    t1 = t1 > 0.f ? t1 : NEG * t1;
    float part = attv.x * t0 + attv.y * t1;
    part += __shfl_xor(part, 1);
    part += __shfl_xor(part, 2);
    part += __shfl_xor(part, 4);
    part += __shfl_xor(part, 8);
    float ex = __expf(part);
    den  += ex;
    acc0 += ex * vs.x;
    acc1 += ex * vs.y;
    if ((lane & 15) == 0) {
        alpha[szt(E + node) * 4 + h] = ex;
        denom_out[szt(node) * 4 + h] = den;
    }
    float2 bv = *reinterpret_cast<const float2*>(&bias[c0]);
    float inv = 1.f / den;
    float o0 = acc0 * inv + bv.x;
    float o1 = acc1 * inv + bv.y;
    *reinterpret_cast<float2*>(&out[szt(node) * HC + c0]) =
        make_float2(o0 > 0.f ? o0 : 0.f, o1 > 0.f ? o1 : 0.f);
}

// ---------------- alpha normalization ----------------

__global__ void k_norm(const int* __restrict__ dst, const float* __restrict__ denom,
                       float* __restrict__ alpha, int n, int E) {
    int e = blockIdx.x * 256 + threadIdx.x;
    int tot = E + n;
    if (e >= tot) return;
    int d = (e < E) ? dst[e] : (e - E);
    float4 a  = *reinterpret_cast<const float4*>(&alpha[szt(e) * 4]);
    float4 dn = *reinterpret_cast<const float4*>(&denom[szt(d) * 4]);
    a.x /= dn.x; a.y /= dn.y; a.z /= dn.z; a.w /= dn.w;
    *reinterpret_cast<float4*>(&alpha[szt(e) * 4]) = a;
}

// ---------------- launch ----------------

extern "C" void kernel_launch(void* const* d_in, const int* in_sizes, int n_in,
                              void* d_out, int out_size, void* d_ws, size_t ws_size,
                              hipStream_t stream) {
    const float* x    = (const float*)d_in[0];
    const int*   ei   = (const int*)d_in[1];
    const float* ea   = (const float*)d_in[2];
    const float* Wl   = (const float*)d_in[3];
    const float* Wr   = (const float*)d_in[4];
    const float* We   = (const float*)d_in[5];
    const float* att  = (const float*)d_in[6];
    const float* bias = (const float*)d_in[7];

    const int n = in_sizes[0] / HC;   // F_IN == 128
    const int E = in_sizes[1] / 2;
    const int* src = ei;
    const int* dst = ei + E;

    char* w = (char*)d_ws;
    size_t off = 0;
    auto alloc = [&](size_t bytes) -> char* {
        char* p = w + off;
        off += (bytes + 255) & ~(size_t)255;
        return p;
    };
    float* xl      = (float*)alloc((size_t)n * HC * 4);
    float* xr      = (float*)alloc((size_t)n * HC * 4);
    float* ea_csr  = (float*)alloc((size_t)E * FE * 4);
    float* denom   = (float*)alloc((size_t)n * 4 * 4);
    int*   cnt     = (int*)  alloc((size_t)n * 4);
    int*   row_off = (int*)  alloc((size_t)(n + 1) * 4);
    int*   cursor  = (int*)  alloc((size_t)n * 4);
    int2*  pairs   = (int2*) alloc((size_t)E * 8);
    int    nb      = (n + 4095) / 4096;
    int*   bsum    = (int*)  alloc((size_t)nb * 4);
    (void)ws_size;

    float* out_p   = (float*)d_out;
    float* alpha_p = (float*)d_out + (size_t)n * HC;

    hipMemsetAsync(cnt, 0, (size_t)n * 4, stream);
    k_count<<<(E + 255) / 256, 256, 0, stream>>>(dst, cnt, E);
    k_scan1<<<nb, 1024, 0, stream>>>(cnt, row_off, bsum, n);
    k_scan2<<<1, 64, 0, stream>>>(bsum, nb);
    k_scan3<<<(n + 256) / 256, 256, 0, stream>>>(bsum, row_off, cursor, n, E);
    k_fill <<<(E + 255) / 256, 256, 0, stream>>>(src, dst, (const float4*)ea, cursor,
                                                 pairs, (float4*)ea_csr, E);
    k_gemm <<<(n + 31) / 32, 256, 0, stream>>>(x, Wl, Wr, xl, xr, n);
    k_fused<<<(n + 3) / 4, 256, 0, stream>>>(xl, xr, ea_csr, pairs, row_off,
                                             We, att, bias, out_p, alpha_p, denom, n, E);
    k_norm <<<(E + n + 255) / 256, 256, 0, stream>>>(dst, denom, alpha_p, n, E);
}

// Round 5
// 717.130 us; speedup vs baseline: 1.4861x; 1.4861x over previous
//
#include <hip/hip_runtime.h>
#include <hip/hip_bf16.h>

#define HC   128   // H*C
#define FE   16    // edge feature dim
#define NEG  0.2f

using bf16 = __hip_bfloat16;

static __device__ __forceinline__ size_t szt(int a) { return (size_t)a; }
static __device__ __forceinline__ float bl(unsigned u) { return __uint_as_float(u << 16); }
static __device__ __forceinline__ float bh(unsigned u) { return __uint_as_float(u & 0xffff0000u); }

// ---------------- CSR build (real edges only; self-loops handled in epilogue) ----------------

__global__ void k_count(const int* __restrict__ dst, int* __restrict__ cnt, int E) {
    int e = blockIdx.x * 256 + threadIdx.x;
    if (e < E) atomicAdd(&cnt[dst[e]], 1);
}

__global__ __launch_bounds__(1024) void k_scan1(const int* __restrict__ cnt,
                                                int* __restrict__ excl,
                                                int* __restrict__ bsum, int n) {
    __shared__ int wsum[16];
    int t = threadIdx.x, lane = t & 63, wv = t >> 6;
    int i = blockIdx.x * 4096 + t * 4;
    int4 c = make_int4(0, 0, 0, 0);
    if (i + 3 < n) c = *reinterpret_cast<const int4*>(&cnt[i]);
    else if (i < n) {
        c.x = cnt[i];
        c.y = (i + 1 < n) ? cnt[i + 1] : 0;
        c.z = (i + 2 < n) ? cnt[i + 2] : 0;
    }
    int tot = c.x + c.y + c.z + c.w;
    int s = tot;
    #pragma unroll
    for (int d = 1; d < 64; d <<= 1) { int u = __shfl_up(s, d); if (lane >= d) s += u; }
    if (lane == 63) wsum[wv] = s;
    __syncthreads();
    if (t < 16) {
        int ws = wsum[t];
        #pragma unroll
        for (int d = 1; d < 16; d <<= 1) { int u = __shfl_up(ws, d); if (t >= d) ws += u; }
        wsum[t] = ws;
    }
    __syncthreads();
    int excl_t = (wv ? wsum[wv - 1] : 0) + (s - tot);
    if (i < n) {
        int4 ro;
        ro.x = excl_t;
        ro.y = ro.x + c.x;
        ro.z = ro.y + c.y;
        ro.w = ro.z + c.z;
        if (i + 3 < n) *reinterpret_cast<int4*>(&excl[i]) = ro;
        else {
            excl[i] = ro.x;
            if (i + 1 < n) excl[i + 1] = ro.y;
            if (i + 2 < n) excl[i + 2] = ro.z;
        }
    }
    if (t == 0) bsum[blockIdx.x] = wsum[15];
}

__global__ void k_scan2(int* __restrict__ bsum, int nb) {
    int t = threadIdx.x;   // 64 threads
    int carry = 0;
    for (int base = 0; base < nb; base += 64) {
        int i = base + t;
        int v = (i < nb) ? bsum[i] : 0;
        int s = v;
        #pragma unroll
        for (int d = 1; d < 64; d <<= 1) { int u = __shfl_up(s, d); if (t >= d) s += u; }
        if (i < nb) bsum[i] = carry + s - v;
        carry += __shfl(s, 63);
    }
}

__global__ void k_scan3(const int* __restrict__ bsum, int* __restrict__ row_off,
                        int* __restrict__ cursor, int n, int E) {
    int i = blockIdx.x * 256 + threadIdx.x;
    if (i < n) {
        int v = row_off[i] + bsum[i >> 12];
        row_off[i] = v;
        cursor[i] = v;
    }
    if (i == n) row_off[n] = E;
}

__global__ void k_fill(const int* __restrict__ src, const int* __restrict__ dst,
                       int* __restrict__ cursor, int2* __restrict__ pairs, int E) {
    int e = blockIdx.x * 256 + threadIdx.x;
    if (e < E) {
        int pos = atomicAdd(&cursor[dst[e]], 1);
        pairs[pos] = make_int2(src[e], e);
    }
}

// ---------------- fused projection GEMM: xl = x@Wl, xr = x@Wr (bf16 outputs) ----------------

__global__ __launch_bounds__(256) void k_gemm(const float* __restrict__ x,
                                              const float* __restrict__ Wl,
                                              const float* __restrict__ Wr,
                                              bf16* __restrict__ xlb,
                                              bf16* __restrict__ xrb, int n) {
    __shared__ float xs[32][HC];
    int t = threadIdx.x;
    int base = blockIdx.x * 32;
    int rmax = n - base; if (rmax > 32) rmax = 32;
    for (int idx = t; idx < 32 * HC; idx += 256) {
        int r = idx >> 7, k = idx & 127;
        xs[r][k] = (r < rmax) ? x[szt(base + r) * HC + k] : 0.f;
    }
    __syncthreads();
    const float* W = (t & 128) ? Wr : Wl;
    bf16*        O = (t & 128) ? xrb : xlb;
    int c = t & 127;
    float acc[32];
    #pragma unroll
    for (int r = 0; r < 32; ++r) acc[r] = 0.f;
    for (int k = 0; k < HC; k += 4) {
        float w0 = W[(k + 0) * HC + c];
        float w1 = W[(k + 1) * HC + c];
        float w2 = W[(k + 2) * HC + c];
        float w3 = W[(k + 3) * HC + c];
        #pragma unroll
        for (int r = 0; r < 32; ++r) {
            float4 xv = *reinterpret_cast<const float4*>(&xs[r][k]);
            acc[r] += xv.x * w0 + xv.y * w1 + xv.z * w2 + xv.w * w3;
        }
    }
    #pragma unroll
    for (int r = 0; r < 32; ++r)
        if (r < rmax) O[szt(base + r) * HC + c] = __float2bfloat16(acc[r]);
}

// ---------------- fused per-node attention + aggregation ----------------
// 1 wave per node. lane = (j = lane>>5 edge slot, cg = lane&31 channel-quad).
// Batch of 2 edges per iteration; every address is per-lane (no readlane, no
// scalar loads). ee inline from LDS We (padded 24B/quad rows: conflict-free
// 2x ds_read_b64) with ea broadcast = 1 shfl per k. bf16 xl gather (8B/lane).
// Head logit reduce = 3 shfl_xor over the 8-lane channel group.

__global__ __launch_bounds__(256) void k_fused(
    const bf16* __restrict__ xlb, const bf16* __restrict__ xrb,
    const float* __restrict__ ea,
    const int2* __restrict__ pairs, const int* __restrict__ row_off,
    const float* __restrict__ We, const float* __restrict__ att,
    const float* __restrict__ bias,
    float* __restrict__ out, float* __restrict__ alpha,
    float* __restrict__ denom_out, int n, int E)
{
    __shared__ float sWe[16 * 192];   // row k at k*192; quad q at q*6 floats (24B)
    for (int i = threadIdx.x; i < 16 * HC; i += 256) {
        int k = i >> 7, c = i & 127;
        sWe[k * 192 + (c >> 2) * 6 + (c & 3)] = We[k * HC + c];
    }
    __syncthreads();

    int lane = threadIdx.x & 63, wv = threadIdx.x >> 6;
    int node = blockIdx.x * 4 + wv;
    if (node >= n) return;
    int j = lane >> 5, cg = lane & 31, kk = cg & 15, h = cg >> 3, cb = cg * 4;

    float4 attv = *reinterpret_cast<const float4*>(att + cb);
    uint2 xru = *reinterpret_cast<const uint2*>(xrb + szt(node) * HC + cb);
    float xr0 = bl(xru.x), xr1 = bh(xru.x), xr2 = bl(xru.y), xr3 = bh(xru.y);

    int beg = row_off[node], end = row_off[node + 1];
    float a0 = 0.f, a1 = 0.f, a2 = 0.f, a3 = 0.f;       // acc
    float s0 = 0.f, s1 = 0.f, s2 = 0.f, s3 = 0.f;       // es (ee sum)
    float den = 0.f;

    if (beg < end) {
        int last = end - 1;
        int q0 = beg + j;           if (q0 > last) q0 = last;
        int2 prC = pairs[q0];
        float eaC = ea[szt(prC.y) * FE + kk];
        uint2 xvC = *reinterpret_cast<const uint2*>(xlb + szt(prC.x) * HC + cb);
        int q1 = beg + 2 + j;       if (q1 > last) q1 = last;
        int2 prN = pairs[q1];

        for (int p = beg; p < end; p += 2) {
            int q2 = p + 4 + j;     if (q2 > last) q2 = last;
            int2 prNN = pairs[q2];
            float eaN = ea[szt(prN.y) * FE + kk];
            uint2 xvN = *reinterpret_cast<const uint2*>(xlb + szt(prN.x) * HC + cb);

            // ee for this lane's edge, 4 channels
            float w0 = 0.f, w1 = 0.f, w2 = 0.f, w3 = 0.f;
            #pragma unroll
            for (int k = 0; k < 16; ++k) {
                float a = __shfl(eaC, (lane & 32) | k);
                const float* wp = &sWe[k * 192 + cg * 6];
                float2 wa = *reinterpret_cast<const float2*>(wp);
                float2 wb = *reinterpret_cast<const float2*>(wp + 2);
                w0 += a * wa.x; w1 += a * wa.y;
                w2 += a * wb.x; w3 += a * wb.y;
            }
            float x0 = bl(xvC.x), x1 = bh(xvC.x), x2 = bl(xvC.y), x3 = bh(xvC.y);
            float t0 = x0 + xr0 + w0; t0 = t0 > 0.f ? t0 : NEG * t0;
            float t1 = x1 + xr1 + w1; t1 = t1 > 0.f ? t1 : NEG * t1;
            float t2 = x2 + xr2 + w2; t2 = t2 > 0.f ? t2 : NEG * t2;
            float t3 = x3 + xr3 + w3; t3 = t3 > 0.f ? t3 : NEG * t3;
            float part = attv.x * t0 + attv.y * t1 + attv.z * t2 + attv.w * t3;
            part += __shfl_xor(part, 1);
            part += __shfl_xor(part, 2);
            part += __shfl_xor(part, 4);
            float ex = __expf(part);   // logits are small: no max-subtraction needed
            if (p + j < end) {
                den += ex;
                a0 += ex * x0; a1 += ex * x1; a2 += ex * x2; a3 += ex * x3;
                s0 += w0; s1 += w1; s2 += w2; s3 += w3;
                if ((cg & 7) == 0) alpha[szt(prC.y) * 4 + h] = ex;
            }
            prC = prN; prN = prNN; eaC = eaN; xvC = xvN;
        }
    }

    // cross-j reduction
    a0 += __shfl_xor(a0, 32); a1 += __shfl_xor(a1, 32);
    a2 += __shfl_xor(a2, 32); a3 += __shfl_xor(a3, 32);
    s0 += __shfl_xor(s0, 32); s1 += __shfl_xor(s1, 32);
    s2 += __shfl_xor(s2, 32); s3 += __shfl_xor(s3, 32);
    den += __shfl_xor(den, 32);

    // self-loop: ee_self = mean of ee over incoming edges (0 if none)
    int deg = end - beg;
    float invd = (deg > 0) ? 1.f / (float)deg : 0.f;
    uint2 xsu = *reinterpret_cast<const uint2*>(xlb + szt(node) * HC + cb);
    float x0 = bl(xsu.x), x1 = bh(xsu.x), x2 = bl(xsu.y), x3 = bh(xsu.y);
    float t0 = x0 + xr0 + s0 * invd; t0 = t0 > 0.f ? t0 : NEG * t0;
    float t1 = x1 + xr1 + s1 * invd; t1 = t1 > 0.f ? t1 : NEG * t1;
    float t2 = x2 + xr2 + s2 * invd; t2 = t2 > 0.f ? t2 : NEG * t2;
    float t3 = x3 + xr3 + s3 * invd; t3 = t3 > 0.f ? t3 : NEG * t3;
    float part = attv.x * t0 + attv.y * t1 + attv.z * t2 + attv.w * t3;
    part += __shfl_xor(part, 1);
    part += __shfl_xor(part, 2);
    part += __shfl_xor(part, 4);
    float ex = __expf(part);
    den += ex;
    a0 += ex * x0; a1 += ex * x1; a2 += ex * x2; a3 += ex * x3;

    if (lane < 32) {
        if ((cg & 7) == 0) {
            alpha[szt(E + node) * 4 + h] = ex;
            denom_out[szt(node) * 4 + h] = den;
        }
        float4 bv = *reinterpret_cast<const float4*>(bias + cb);
        float inv = 1.f / den;
        float4 o;
        o.x = a0 * inv + bv.x; o.x = o.x > 0.f ? o.x : 0.f;
        o.y = a1 * inv + bv.y; o.y = o.y > 0.f ? o.y : 0.f;
        o.z = a2 * inv + bv.z; o.z = o.z > 0.f ? o.z : 0.f;
        o.w = a3 * inv + bv.w; o.w = o.w > 0.f ? o.w : 0.f;
        *reinterpret_cast<float4*>(out + szt(node) * HC + cb) = o;
    }
}

// ---------------- alpha normalization ----------------

__global__ void k_norm(const int* __restrict__ dst, const float* __restrict__ denom,
                       float* __restrict__ alpha, int n, int E) {
    int e = blockIdx.x * 256 + threadIdx.x;
    int tot = E + n;
    if (e >= tot) return;
    int d = (e < E) ? dst[e] : (e - E);
    float4 a  = *reinterpret_cast<const float4*>(&alpha[szt(e) * 4]);
    float4 dn = *reinterpret_cast<const float4*>(&denom[szt(d) * 4]);
    a.x /= dn.x; a.y /= dn.y; a.z /= dn.z; a.w /= dn.w;
    *reinterpret_cast<float4*>(&alpha[szt(e) * 4]) = a;
}

// ---------------- launch ----------------

extern "C" void kernel_launch(void* const* d_in, const int* in_sizes, int n_in,
                              void* d_out, int out_size, void* d_ws, size_t ws_size,
                              hipStream_t stream) {
    const float* x    = (const float*)d_in[0];
    const int*   ei   = (const int*)d_in[1];
    const float* ea   = (const float*)d_in[2];
    const float* Wl   = (const float*)d_in[3];
    const float* Wr   = (const float*)d_in[4];
    const float* We   = (const float*)d_in[5];
    const float* att  = (const float*)d_in[6];
    const float* bias = (const float*)d_in[7];

    const int n = in_sizes[0] / HC;   // F_IN == 128
    const int E = in_sizes[1] / 2;
    const int* src = ei;
    const int* dst = ei + E;

    char* w = (char*)d_ws;
    size_t off = 0;
    auto alloc = [&](size_t bytes) -> char* {
        char* p = w + off;
        off += (bytes + 255) & ~(size_t)255;
        return p;
    };
    bf16*  xlb     = (bf16*) alloc((size_t)n * HC * 2);
    bf16*  xrb     = (bf16*) alloc((size_t)n * HC * 2);
    float* denom   = (float*)alloc((size_t)n * 4 * 4);
    int*   cnt     = (int*)  alloc((size_t)n * 4);
    int*   row_off = (int*)  alloc((size_t)(n + 1) * 4);
    int*   cursor  = (int*)  alloc((size_t)n * 4);
    int2*  pairs   = (int2*) alloc((size_t)E * 8);
    int    nb      = (n + 4095) / 4096;
    int*   bsum    = (int*)  alloc((size_t)nb * 4);
    (void)ws_size;

    float* out_p   = (float*)d_out;
    float* alpha_p = (float*)d_out + (size_t)n * HC;

    hipMemsetAsync(cnt, 0, (size_t)n * 4, stream);
    k_count<<<(E + 255) / 256, 256, 0, stream>>>(dst, cnt, E);
    k_scan1<<<nb, 1024, 0, stream>>>(cnt, row_off, bsum, n);
    k_scan2<<<1, 64, 0, stream>>>(bsum, nb);
    k_scan3<<<(n + 256) / 256, 256, 0, stream>>>(bsum, row_off, cursor, n, E);
    k_fill <<<(E + 255) / 256, 256, 0, stream>>>(src, dst, cursor, pairs, E);
    k_gemm <<<(n + 31) / 32, 256, 0, stream>>>(x, Wl, Wr, xlb, xrb, n);
    k_fused<<<(n + 3) / 4, 256, 0, stream>>>(xlb, xrb, ea, pairs, row_off,
                                             We, att, bias, out_p, alpha_p, denom, n, E);
    k_norm <<<(E + n + 255) / 256, 256, 0, stream>>>(dst, denom, alpha_p, n, E);
}

// Round 7
// 707.214 us; speedup vs baseline: 1.5070x; 1.0140x over previous
//
#include <hip/hip_runtime.h>
#include <hip/hip_bf16.h>

#define HC   128   // H*C
#define FE   16    // edge feature dim
#define NEG  0.2f

using bf16 = __hip_bfloat16;
typedef _Float16 half2v __attribute__((ext_vector_type(2)));

static __device__ __forceinline__ size_t szt(int a) { return (size_t)a; }
static __device__ __forceinline__ float bl(unsigned u) { return __uint_as_float(u << 16); }
static __device__ __forceinline__ float bh(unsigned u) { return __uint_as_float(u & 0xffff0000u); }

static __device__ __forceinline__ unsigned pk(float x, float y) {
    auto h = __builtin_amdgcn_cvt_pkrtz(x, y);   // __fp16 ext_vector(2)
    return __builtin_bit_cast(unsigned, h);
}
static __device__ __forceinline__ float dot2(unsigned a, unsigned b, float c) {
#if __has_builtin(__builtin_amdgcn_fdot2)
    return __builtin_amdgcn_fdot2(__builtin_bit_cast(half2v, a),
                                  __builtin_bit_cast(half2v, b), c, false);
#else
    half2v av = __builtin_bit_cast(half2v, a), bv = __builtin_bit_cast(half2v, b);
    return c + (float)av.x * (float)bv.x + (float)av.y * (float)bv.y;
#endif
}

// ---------------- CSR build ----------------

__global__ void k_count(const int* __restrict__ dst, int* __restrict__ cnt, int E) {
    int e = blockIdx.x * 256 + threadIdx.x;
    if (e < E) atomicAdd(&cnt[dst[e]], 1);
}

__global__ __launch_bounds__(1024) void k_scan1(const int* __restrict__ cnt,
                                                int* __restrict__ excl,
                                                int* __restrict__ bsum, int n) {
    __shared__ int wsum[16];
    int t = threadIdx.x, lane = t & 63, wv = t >> 6;
    int i = blockIdx.x * 4096 + t * 4;
    int4 c = make_int4(0, 0, 0, 0);
    if (i + 3 < n) c = *reinterpret_cast<const int4*>(&cnt[i]);
    else if (i < n) {
        c.x = cnt[i];
        c.y = (i + 1 < n) ? cnt[i + 1] : 0;
        c.z = (i + 2 < n) ? cnt[i + 2] : 0;
    }
    int tot = c.x + c.y + c.z + c.w;
    int s = tot;
    #pragma unroll
    for (int d = 1; d < 64; d <<= 1) { int u = __shfl_up(s, d); if (lane >= d) s += u; }
    if (lane == 63) wsum[wv] = s;
    __syncthreads();
    if (t < 16) {
        int ws = wsum[t];
        #pragma unroll
        for (int d = 1; d < 16; d <<= 1) { int u = __shfl_up(ws, d); if (t >= d) ws += u; }
        wsum[t] = ws;
    }
    __syncthreads();
    int excl_t = (wv ? wsum[wv - 1] : 0) + (s - tot);
    if (i < n) {
        int4 ro;
        ro.x = excl_t;
        ro.y = ro.x + c.x;
        ro.z = ro.y + c.y;
        ro.w = ro.z + c.z;
        if (i + 3 < n) *reinterpret_cast<int4*>(&excl[i]) = ro;
        else {
            excl[i] = ro.x;
            if (i + 1 < n) excl[i + 1] = ro.y;
            if (i + 2 < n) excl[i + 2] = ro.z;
        }
    }
    if (t == 0) bsum[blockIdx.x] = wsum[15];
}

__global__ void k_scan2(int* __restrict__ bsum, int nb) {
    int t = threadIdx.x;   // 64 threads
    int carry = 0;
    for (int base = 0; base < nb; base += 64) {
        int i = base + t;
        int v = (i < nb) ? bsum[i] : 0;
        int s = v;
        #pragma unroll
        for (int d = 1; d < 64; d <<= 1) { int u = __shfl_up(s, d); if (t >= d) s += u; }
        if (i < nb) bsum[i] = carry + s - v;
        carry += __shfl(s, 63);
    }
}

__global__ void k_scan3(const int* __restrict__ bsum, int* __restrict__ row_off,
                        int* __restrict__ cursor, int n, int E) {
    int i = blockIdx.x * 256 + threadIdx.x;
    if (i < n) {
        int v = row_off[i] + bsum[i >> 12];
        row_off[i] = v;
        cursor[i] = v;
    }
    if (i == n) row_off[n] = E;
}

__global__ void k_fill(const int* __restrict__ src, const int* __restrict__ dst,
                       int* __restrict__ cursor, int2* __restrict__ pairs, int E) {
    int e = blockIdx.x * 256 + threadIdx.x;
    if (e < E) {
        int pos = atomicAdd(&cursor[dst[e]], 1);
        pairs[pos] = make_int2(src[e], e);
    }
}

// ---------------- projection GEMM: xl = x@Wl, xr = x@Wr (bf16 out) ----------------

__global__ __launch_bounds__(256) void k_gemm(const float* __restrict__ x,
                                              const float* __restrict__ Wl,
                                              const float* __restrict__ Wr,
                                              bf16* __restrict__ xlb,
                                              bf16* __restrict__ xrb, int n) {
    __shared__ float xs[32][HC];
    int t = threadIdx.x;
    int base = blockIdx.x * 32;
    int rmax = n - base; if (rmax > 32) rmax = 32;
    for (int idx = t; idx < 32 * HC; idx += 256) {
        int r = idx >> 7, k = idx & 127;
        xs[r][k] = (r < rmax) ? x[szt(base + r) * HC + k] : 0.f;
    }
    __syncthreads();
    const float* W = (t & 128) ? Wr : Wl;
    bf16*        O = (t & 128) ? xrb : xlb;
    int c = t & 127;
    float acc[32];
    #pragma unroll
    for (int r = 0; r < 32; ++r) acc[r] = 0.f;
    for (int k = 0; k < HC; k += 4) {
        float w0 = W[(k + 0) * HC + c];
        float w1 = W[(k + 1) * HC + c];
        float w2 = W[(k + 2) * HC + c];
        float w3 = W[(k + 3) * HC + c];
        #pragma unroll
        for (int r = 0; r < 32; ++r) {
            float4 xv = *reinterpret_cast<const float4*>(&xs[r][k]);
            acc[r] += xv.x * w0 + xv.y * w1 + xv.z * w2 + xv.w * w3;
        }
    }
    #pragma unroll
    for (int r = 0; r < 32; ++r)
        if (r < rmax) O[szt(base + r) * HC + c] = __float2bfloat16(acc[r]);
}

// ---------------- self-loop: ex_self from mean incoming edge_attr ----------------
// wave per node: 4-way parallel segment-sum of ea, then ee/logit for the loop edge.

__global__ __launch_bounds__(256) void k_self(
    const bf16* __restrict__ xlb, const bf16* __restrict__ xrb,
    const float* __restrict__ ea, const int2* __restrict__ pairs,
    const int* __restrict__ row_off, const float* __restrict__ We,
    const float* __restrict__ att, float* __restrict__ exself, int n)
{
    int lane = threadIdx.x & 63, wv = threadIdx.x >> 6;
    int node = blockIdx.x * 4 + wv;
    if (node >= n) return;
    int beg = row_off[node], end = row_off[node + 1];
    int js = lane >> 4, f = lane & 15;
    float sum = 0.f;
    for (int p = beg + js; p < end; p += 4) {
        int2 pr = pairs[p];
        sum += ea[szt(pr.y) * FE + f];
    }
    sum += __shfl_xor(sum, 16);
    sum += __shfl_xor(sum, 32);
    int deg = end - beg;
    float mean = (deg > 0) ? sum / (float)deg : 0.f;   // lane k holds feature k (replicated)

    int c0 = lane * 2, h = lane >> 4;
    float e0 = 0.f, e1 = 0.f;
    #pragma unroll
    for (int k = 0; k < FE; ++k) {
        float a = __shfl(mean, k);
        float2 w = *reinterpret_cast<const float2*>(We + k * HC + c0);
        e0 += a * w.x; e1 += a * w.y;
    }
    unsigned xu = *reinterpret_cast<const unsigned*>(xlb + szt(node) * HC + c0);
    unsigned ru = *reinterpret_cast<const unsigned*>(xrb + szt(node) * HC + c0);
    float2 av = *reinterpret_cast<const float2*>(att + c0);
    float t0 = bl(xu) + bl(ru) + e0; t0 = t0 > 0.f ? t0 : NEG * t0;
    float t1 = bh(xu) + bh(ru) + e1; t1 = t1 > 0.f ? t1 : NEG * t1;
    float part = av.x * t0 + av.y * t1;
    part += __shfl_xor(part, 1);
    part += __shfl_xor(part, 2);
    part += __shfl_xor(part, 4);
    part += __shfl_xor(part, 8);
    float ex = __expf(part);
    if ((lane & 15) == 0) exself[szt(node) * 4 + h] = ex;
}

// ---------------- edge logits (edge-parallel, original edge order) ----------------
// wave handles 2 edges: j = lane>>5 edge slot, cg = lane&31 channel-quad (4 ch).
// ee via f16 dot2: ea packed pairs broadcast by shfl; We f16-packed in LDS at
// 24B quad stride (conflict-free 2x ds_read_b64). No loop-carried state.

__global__ __launch_bounds__(256) void k_logit(
    const bf16* __restrict__ xlb, const bf16* __restrict__ xrb,
    const float* __restrict__ ea,
    const int* __restrict__ srcA, const int* __restrict__ dstA,
    const float* __restrict__ We, const float* __restrict__ att,
    float* __restrict__ exe, int E, int stride8)
{
    __shared__ unsigned sWe[8 * 192];   // [kp][cg*6 + i], i=0..3 used
    for (int i = threadIdx.x; i < 8 * HC; i += 256) {
        int kp = i >> 7, c = i & 127;
        sWe[kp * 192 + (c >> 2) * 6 + (c & 3)] =
            pk(We[(2 * kp) * HC + c], We[(2 * kp + 1) * HC + c]);
    }
    __syncthreads();

    int lane = threadIdx.x & 63, wv = threadIdx.x >> 6;
    int j = lane >> 5, cg = lane & 31, cb = cg * 4, h = cg >> 3;
    float4 attv = *reinterpret_cast<const float4*>(att + cb);

    for (int e = blockIdx.x * 8 + wv * 2 + j; e < E + j; e += stride8) {
        int ec = (e < E) ? e : (E - 1);
        int s = srcA[ec], d = dstA[ec];
        float2 af = *reinterpret_cast<const float2*>(ea + szt(ec) * FE + (cg & 7) * 2);
        unsigned eap = pk(af.x, af.y);
        uint2 xv = *reinterpret_cast<const uint2*>(xlb + szt(s) * HC + cb);
        uint2 rv = *reinterpret_cast<const uint2*>(xrb + szt(d) * HC + cb);

        float w0 = 0.f, w1 = 0.f, w2 = 0.f, w3 = 0.f;
        #pragma unroll
        for (int kp = 0; kp < 8; ++kp) {
            unsigned a = __shfl(eap, (lane & 32) | kp);
            const unsigned* wp = &sWe[kp * 192 + cg * 6];
            uint2 wa = *reinterpret_cast<const uint2*>(wp);
            uint2 wb = *reinterpret_cast<const uint2*>(wp + 2);
            w0 = dot2(a, wa.x, w0);
            w1 = dot2(a, wa.y, w1);
            w2 = dot2(a, wb.x, w2);
            w3 = dot2(a, wb.y, w3);
        }
        float t0 = bl(xv.x) + bl(rv.x) + w0; t0 = t0 > 0.f ? t0 : NEG * t0;
        float t1 = bh(xv.x) + bh(rv.x) + w1; t1 = t1 > 0.f ? t1 : NEG * t1;
        float t2 = bl(xv.y) + bl(rv.y) + w2; t2 = t2 > 0.f ? t2 : NEG * t2;
        float t3 = bh(xv.y) + bh(rv.y) + w3; t3 = t3 > 0.f ? t3 : NEG * t3;
        float part = attv.x * t0 + attv.y * t1 + attv.z * t2 + attv.w * t3;
        part += __shfl_xor(part, 1);
        part += __shfl_xor(part, 2);
        part += __shfl_xor(part, 4);
        float ex = __expf(part);   // logits are small: no max-subtraction needed
        if (e < E && (cg & 7) == 0) exe[szt(e) * 4 + h] = ex;
    }
}

// ---------------- aggregation (node-parallel) ----------------
// wave per node: j = lane>>4 edge slot (4), cg = lane&15 (8 ch), h = cg>>2.
// den = sum ex; acc = sum ex * xl[src]; + self-loop; writes out/denom/self-alpha.

__global__ __launch_bounds__(256) void k_aggr(
    const bf16* __restrict__ xlb, const float* __restrict__ exe,
    const float* __restrict__ exself,
    const int2* __restrict__ pairs, const int* __restrict__ row_off,
    const float* __restrict__ bias, float* __restrict__ out,
    float* __restrict__ alpha, float* __restrict__ denom_out, int n, int E)
{
    int lane = threadIdx.x & 63, wv = threadIdx.x >> 6;
    int node = blockIdx.x * 4 + wv;
    if (node >= n) return;
    int j = lane >> 4, cg = lane & 15, cb = cg * 8, h = cg >> 2;
    int beg = row_off[node], end = row_off[node + 1];
    float acc[8];
    #pragma unroll
    for (int i = 0; i < 8; ++i) acc[i] = 0.f;
    float den = 0.f;

    if (beg < end) {
        int last = end - 1;
        int p0 = beg + j; if (p0 > last) p0 = last;
        int2 pr = pairs[p0];
        float ex = exe[szt(pr.y) * 4 + h];
        uint4 xv = *reinterpret_cast<const uint4*>(xlb + szt(pr.x) * HC + cb);
        for (int p = beg; p < end; p += 4) {
            int pn = p + 4 + j; if (pn > last) pn = last;
            int2 prN = pairs[pn];
            float exN = exe[szt(prN.y) * 4 + h];
            uint4 xvN = *reinterpret_cast<const uint4*>(xlb + szt(prN.x) * HC + cb);
            if (p + j < end) {
                den += ex;
                acc[0] += ex * bl(xv.x); acc[1] += ex * bh(xv.x);
                acc[2] += ex * bl(xv.y); acc[3] += ex * bh(xv.y);
                acc[4] += ex * bl(xv.z); acc[5] += ex * bh(xv.z);
                acc[6] += ex * bl(xv.w); acc[7] += ex * bh(xv.w);
            }
            pr = prN; ex = exN; xv = xvN;
        }
    }
    #pragma unroll
    for (int i = 0; i < 8; ++i) {
        acc[i] += __shfl_xor(acc[i], 16);
        acc[i] += __shfl_xor(acc[i], 32);
    }
    den += __shfl_xor(den, 16);
    den += __shfl_xor(den, 32);

    float exs = exself[szt(node) * 4 + h];
    uint4 xs = *reinterpret_cast<const uint4*>(xlb + szt(node) * HC + cb);
    den += exs;
    acc[0] += exs * bl(xs.x); acc[1] += exs * bh(xs.x);
    acc[2] += exs * bl(xs.y); acc[3] += exs * bh(xs.y);
    acc[4] += exs * bl(xs.z); acc[5] += exs * bh(xs.z);
    acc[6] += exs * bl(xs.w); acc[7] += exs * bh(xs.w);

    if (j == 0) {
        float inv = 1.f / den;
        float4 b0 = *reinterpret_cast<const float4*>(bias + cb);
        float4 b1 = *reinterpret_cast<const float4*>(bias + cb + 4);
        float4 o0, o1;
        o0.x = acc[0] * inv + b0.x; o0.x = o0.x > 0.f ? o0.x : 0.f;
        o0.y = acc[1] * inv + b0.y; o0.y = o0.y > 0.f ? o0.y : 0.f;
        o0.z = acc[2] * inv + b0.z; o0.z = o0.z > 0.f ? o0.z : 0.f;
        o0.w = acc[3] * inv + b0.w; o0.w = o0.w > 0.f ? o0.w : 0.f;
        o1.x = acc[4] * inv + b1.x; o1.x = o1.x > 0.f ? o1.x : 0.f;
        o1.y = acc[5] * inv + b1.y; o1.y = o1.y > 0.f ? o1.y : 0.f;
        o1.z = acc[6] * inv + b1.z; o1.z = o1.z > 0.f ? o1.z : 0.f;
        o1.w = acc[7] * inv + b1.w; o1.w = o1.w > 0.f ? o1.w : 0.f;
        *reinterpret_cast<float4*>(out + szt(node) * HC + cb) = o0;
        *reinterpret_cast<float4*>(out + szt(node) * HC + cb + 4) = o1;
        if ((cg & 3) == 0) {
            denom_out[szt(node) * 4 + h] = den;
            alpha[szt(E + node) * 4 + h] = exs * inv;
        }
    }
}

// ---------------- alpha normalization (real edges) ----------------

__global__ void k_norm(const int* __restrict__ dst, const float* __restrict__ denom,
                       const float* __restrict__ exe, float* __restrict__ alpha, int E) {
    int e = blockIdx.x * 256 + threadIdx.x;
    if (e >= E) return;
    int d = dst[e];
    float4 a  = *reinterpret_cast<const float4*>(&exe[szt(e) * 4]);
    float4 dn = *reinterpret_cast<const float4*>(&denom[szt(d) * 4]);
    a.x /= dn.x; a.y /= dn.y; a.z /= dn.z; a.w /= dn.w;
    *reinterpret_cast<float4*>(&alpha[szt(e) * 4]) = a;
}

// ---------------- launch ----------------

extern "C" void kernel_launch(void* const* d_in, const int* in_sizes, int n_in,
                              void* d_out, int out_size, void* d_ws, size_t ws_size,
                              hipStream_t stream) {
    const float* x    = (const float*)d_in[0];
    const int*   ei   = (const int*)d_in[1];
    const float* ea   = (const float*)d_in[2];
    const float* Wl   = (const float*)d_in[3];
    const float* Wr   = (const float*)d_in[4];
    const float* We   = (const float*)d_in[5];
    const float* att  = (const float*)d_in[6];
    const float* bias = (const float*)d_in[7];

    const int n = in_sizes[0] / HC;   // F_IN == 128
    const int E = in_sizes[1] / 2;
    const int* src = ei;
    const int* dst = ei + E;

    char* w = (char*)d_ws;
    size_t off = 0;
    auto alloc = [&](size_t bytes) -> char* {
        char* p = w + off;
        off += (bytes + 255) & ~(size_t)255;
        return p;
    };
    bf16*  xlb     = (bf16*) alloc((size_t)n * HC * 2);
    bf16*  xrb     = (bf16*) alloc((size_t)n * HC * 2);
    float* exe     = (float*)alloc((size_t)E * 4 * 4);
    float* exself  = (float*)alloc((size_t)n * 4 * 4);
    float* denom   = (float*)alloc((size_t)n * 4 * 4);
    int*   cnt     = (int*)  alloc((size_t)n * 4);
    int*   row_off = (int*)  alloc((size_t)(n + 1) * 4);
    int*   cursor  = (int*)  alloc((size_t)n * 4);
    int2*  pairs   = (int2*) alloc((size_t)E * 8);
    int    nb      = (n + 4095) / 4096;
    int*   bsum    = (int*)  alloc((size_t)nb * 4);
    (void)ws_size;

    float* out_p   = (float*)d_out;
    float* alpha_p = (float*)d_out + (size_t)n * HC;

    (void)hipMemsetAsync(cnt, 0, (size_t)n * 4, stream);
    k_count<<<(E + 255) / 256, 256, 0, stream>>>(dst, cnt, E);
    k_scan1<<<nb, 1024, 0, stream>>>(cnt, row_off, bsum, n);
    k_scan2<<<1, 64, 0, stream>>>(bsum, nb);
    k_scan3<<<(n + 256) / 256, 256, 0, stream>>>(bsum, row_off, cursor, n, E);
    k_fill <<<(E + 255) / 256, 256, 0, stream>>>(src, dst, cursor, pairs, E);
    k_gemm <<<(n + 31) / 32, 256, 0, stream>>>(x, Wl, Wr, xlb, xrb, n);
    k_self <<<(n + 3) / 4, 256, 0, stream>>>(xlb, xrb, ea, pairs, row_off, We, att,
                                             exself, n);
    {
        int nblk = 16384;
        k_logit<<<nblk, 256, 0, stream>>>(xlb, xrb, ea, src, dst, We, att,
                                          exe, E, nblk * 8);
    }
    k_aggr <<<(n + 3) / 4, 256, 0, stream>>>(xlb, exe, exself, pairs, row_off,
                                             bias, out_p, alpha_p, denom, n, E);
    k_norm <<<(E + 255) / 256, 256, 0, stream>>>(dst, denom, exe, alpha_p, E);
}

// Round 8
// 618.714 us; speedup vs baseline: 1.7225x; 1.1430x over previous
//
#include <hip/hip_runtime.h>
#include <hip/hip_bf16.h>

#define HC   128   // H*C
#define FE   16    // edge feature dim
#define NEG  0.2f

using bf16 = __hip_bfloat16;
typedef _Float16 half2v __attribute__((ext_vector_type(2)));
typedef short s16x8 __attribute__((ext_vector_type(8)));
typedef float f32x4 __attribute__((ext_vector_type(4)));

static __device__ __forceinline__ size_t szt(int a) { return (size_t)a; }
static __device__ __forceinline__ float bl(unsigned u) { return __uint_as_float(u << 16); }
static __device__ __forceinline__ float bh(unsigned u) { return __uint_as_float(u & 0xffff0000u); }

static __device__ __forceinline__ unsigned pk(float x, float y) {
    auto h = __builtin_amdgcn_cvt_pkrtz(x, y);   // __fp16 ext_vector(2)
    return __builtin_bit_cast(unsigned, h);
}
static __device__ __forceinline__ float dot2(unsigned a, unsigned b, float c) {
#if __has_builtin(__builtin_amdgcn_fdot2)
    return __builtin_amdgcn_fdot2(__builtin_bit_cast(half2v, a),
                                  __builtin_bit_cast(half2v, b), c, false);
#else
    half2v av = __builtin_bit_cast(half2v, a), bv = __builtin_bit_cast(half2v, b);
    return c + (float)av.x * (float)bv.x + (float)av.y * (float)bv.y;
#endif
}
static __device__ __forceinline__ short b16rne(float f) {
    unsigned u = __float_as_uint(f);
    unsigned r = (u + 0x7fffu + ((u >> 16) & 1u)) >> 16;
    return (short)r;
}

// ---------------- CSR build ----------------

__global__ void k_count(const int* __restrict__ dst, int* __restrict__ cnt, int E) {
    int e = blockIdx.x * 256 + threadIdx.x;
    if (e < E) atomicAdd(&cnt[dst[e]], 1);
}

__global__ __launch_bounds__(1024) void k_scan1(const int* __restrict__ cnt,
                                                int* __restrict__ excl,
                                                int* __restrict__ bsum, int n) {
    __shared__ int wsum[16];
    int t = threadIdx.x, lane = t & 63, wv = t >> 6;
    int i = blockIdx.x * 4096 + t * 4;
    int4 c = make_int4(0, 0, 0, 0);
    if (i + 3 < n) c = *reinterpret_cast<const int4*>(&cnt[i]);
    else if (i < n) {
        c.x = cnt[i];
        c.y = (i + 1 < n) ? cnt[i + 1] : 0;
        c.z = (i + 2 < n) ? cnt[i + 2] : 0;
    }
    int tot = c.x + c.y + c.z + c.w;
    int s = tot;
    #pragma unroll
    for (int d = 1; d < 64; d <<= 1) { int u = __shfl_up(s, d); if (lane >= d) s += u; }
    if (lane == 63) wsum[wv] = s;
    __syncthreads();
    if (t < 16) {
        int ws = wsum[t];
        #pragma unroll
        for (int d = 1; d < 16; d <<= 1) { int u = __shfl_up(ws, d); if (t >= d) ws += u; }
        wsum[t] = ws;
    }
    __syncthreads();
    int excl_t = (wv ? wsum[wv - 1] : 0) + (s - tot);
    if (i < n) {
        int4 ro;
        ro.x = excl_t;
        ro.y = ro.x + c.x;
        ro.z = ro.y + c.y;
        ro.w = ro.z + c.z;
        if (i + 3 < n) *reinterpret_cast<int4*>(&excl[i]) = ro;
        else {
            excl[i] = ro.x;
            if (i + 1 < n) excl[i + 1] = ro.y;
            if (i + 2 < n) excl[i + 2] = ro.z;
        }
    }
    if (t == 0) bsum[blockIdx.x] = wsum[15];
}

__global__ void k_scan2(int* __restrict__ bsum, int nb) {
    int t = threadIdx.x;   // 64 threads
    int carry = 0;
    for (int base = 0; base < nb; base += 64) {
        int i = base + t;
        int v = (i < nb) ? bsum[i] : 0;
        int s = v;
        #pragma unroll
        for (int d = 1; d < 64; d <<= 1) { int u = __shfl_up(s, d); if (t >= d) s += u; }
        if (i < nb) bsum[i] = carry + s - v;
        carry += __shfl(s, 63);
    }
}

__global__ void k_scan3(const int* __restrict__ bsum, int* __restrict__ row_off,
                        int* __restrict__ cursor, int n, int E) {
    int i = blockIdx.x * 256 + threadIdx.x;
    if (i < n) {
        int v = row_off[i] + bsum[i >> 12];
        row_off[i] = v;
        cursor[i] = v;
    }
    if (i == n) row_off[n] = E;
}

__global__ void k_fill(const int* __restrict__ src, const int* __restrict__ dst,
                       int* __restrict__ cursor, int2* __restrict__ pairs, int E) {
    int e = blockIdx.x * 256 + threadIdx.x;
    if (e < E) {
        int pos = atomicAdd(&cursor[dst[e]], 1);
        pairs[pos] = make_int2(src[e], e);
    }
}

// ---------------- weight prep: [Wl|Wr] -> bf16 MFMA B-fragments ----------------
// Wcf[(kt*16+nt)*64+lane] = 8 bf16: B[k=kt*32+(lane>>4)*8+j][col=nt*16+(lane&15)]

__global__ void k_wprep(const float* __restrict__ Wl, const float* __restrict__ Wr,
                        s16x8* __restrict__ Wcf) {
    int idx = blockIdx.x * 256 + threadIdx.x;
    if (idx >= 4096) return;
    int kt = idx >> 10, nt = (idx >> 6) & 15, lane = idx & 63;
    int col = nt * 16 + (lane & 15);
    const float* W = (col < HC) ? Wl : Wr;
    int c = (col < HC) ? col : col - HC;
    s16x8 v;
    #pragma unroll
    for (int j = 0; j < 8; ++j) {
        int k = kt * 32 + (lane >> 4) * 8 + j;
        v[j] = b16rne(W[k * HC + c]);
    }
    Wcf[idx] = v;
}

// ---------------- projection GEMM via MFMA: [xl|xr] = x @ [Wl|Wr] ----------------
// block = 4 waves, 16 rows x 256 cols. Wave w covers cols [w*64, w*64+64).
// A-frag per lane: x[m0 + (lane&15)][kt*32 + (lane>>4)*8 + j], f32->bf16 in reg.
// No LDS, no barriers.

__global__ __launch_bounds__(256) void k_gemm2(const float* __restrict__ x,
                                               const s16x8* __restrict__ Wcf,
                                               bf16* __restrict__ xlb,
                                               bf16* __restrict__ xrb, int n) {
    int t = threadIdx.x, lane = t & 63, w = t >> 6;
    int m0 = blockIdx.x * 16;
    int arow = m0 + (lane & 15);
    if (arow >= n) arow = n - 1;
    const float* xrow = x + szt(arow) * HC + (lane >> 4) * 8;

    f32x4 acc[4];
    #pragma unroll
    for (int nt = 0; nt < 4; ++nt) acc[nt] = (f32x4){0.f, 0.f, 0.f, 0.f};

    #pragma unroll
    for (int kt = 0; kt < 4; ++kt) {
        float4 a0 = *reinterpret_cast<const float4*>(xrow + kt * 32);
        float4 a1 = *reinterpret_cast<const float4*>(xrow + kt * 32 + 4);
        s16x8 af;
        af[0] = b16rne(a0.x); af[1] = b16rne(a0.y);
        af[2] = b16rne(a0.z); af[3] = b16rne(a0.w);
        af[4] = b16rne(a1.x); af[5] = b16rne(a1.y);
        af[6] = b16rne(a1.z); af[7] = b16rne(a1.w);
        #pragma unroll
        for (int nt = 0; nt < 4; ++nt) {
            s16x8 bf = Wcf[(kt * 16 + w * 4 + nt) * 64 + lane];
            acc[nt] = __builtin_amdgcn_mfma_f32_16x16x32_bf16(af, bf, acc[nt], 0, 0, 0);
        }
    }

    // C/D layout: col = lane&15, row = (lane>>4)*4 + q  [m89-verified]
    bf16* O = (w < 2) ? xlb : xrb;
    int colb = (w & 1) * 64;
    #pragma unroll
    for (int nt = 0; nt < 4; ++nt) {
        int col = colb + nt * 16 + (lane & 15);
        #pragma unroll
        for (int q = 0; q < 4; ++q) {
            int r = m0 + (lane >> 4) * 4 + q;
            if (r < n) O[szt(r) * HC + col] = __float2bfloat16(acc[nt][q]);
        }
    }
}

// ---------------- self-loop: ex_self from mean incoming edge_attr ----------------

__global__ __launch_bounds__(256) void k_self(
    const bf16* __restrict__ xlb, const bf16* __restrict__ xrb,
    const float* __restrict__ ea, const int2* __restrict__ pairs,
    const int* __restrict__ row_off, const float* __restrict__ We,
    const float* __restrict__ att, float* __restrict__ exself, int n)
{
    int lane = threadIdx.x & 63, wv = threadIdx.x >> 6;
    int node = blockIdx.x * 4 + wv;
    if (node >= n) return;
    int beg = row_off[node], end = row_off[node + 1];
    int js = lane >> 4, f = lane & 15;
    float sum = 0.f;
    for (int p = beg + js; p < end; p += 4) {
        int2 pr = pairs[p];
        sum += ea[szt(pr.y) * FE + f];
    }
    sum += __shfl_xor(sum, 16);
    sum += __shfl_xor(sum, 32);
    int deg = end - beg;
    float mean = (deg > 0) ? sum / (float)deg : 0.f;   // lane k holds feature k (replicated)

    int c0 = lane * 2, h = lane >> 4;
    float e0 = 0.f, e1 = 0.f;
    #pragma unroll
    for (int k = 0; k < FE; ++k) {
        float a = __shfl(mean, k);
        float2 w = *reinterpret_cast<const float2*>(We + k * HC + c0);
        e0 += a * w.x; e1 += a * w.y;
    }
    unsigned xu = *reinterpret_cast<const unsigned*>(xlb + szt(node) * HC + c0);
    unsigned ru = *reinterpret_cast<const unsigned*>(xrb + szt(node) * HC + c0);
    float2 av = *reinterpret_cast<const float2*>(att + c0);
    float t0 = bl(xu) + bl(ru) + e0; t0 = t0 > 0.f ? t0 : NEG * t0;
    float t1 = bh(xu) + bh(ru) + e1; t1 = t1 > 0.f ? t1 : NEG * t1;
    float part = av.x * t0 + av.y * t1;
    part += __shfl_xor(part, 1);
    part += __shfl_xor(part, 2);
    part += __shfl_xor(part, 4);
    part += __shfl_xor(part, 8);
    float ex = __expf(part);
    if ((lane & 15) == 0) exself[szt(node) * 4 + h] = ex;
}

// ---------------- edge logits (edge-parallel, original edge order) ----------------

__global__ __launch_bounds__(256) void k_logit(
    const bf16* __restrict__ xlb, const bf16* __restrict__ xrb,
    const float* __restrict__ ea,
    const int* __restrict__ srcA, const int* __restrict__ dstA,
    const float* __restrict__ We, const float* __restrict__ att,
    float* __restrict__ exe, int E, int stride8)
{
    __shared__ unsigned sWe[8 * 192];   // [kp][cg*6 + i], i=0..3 used
    for (int i = threadIdx.x; i < 8 * HC; i += 256) {
        int kp = i >> 7, c = i & 127;
        sWe[kp * 192 + (c >> 2) * 6 + (c & 3)] =
            pk(We[(2 * kp) * HC + c], We[(2 * kp + 1) * HC + c]);
    }
    __syncthreads();

    int lane = threadIdx.x & 63, wv = threadIdx.x >> 6;
    int j = lane >> 5, cg = lane & 31, cb = cg * 4, h = cg >> 3;
    float4 attv = *reinterpret_cast<const float4*>(att + cb);

    for (int e = blockIdx.x * 8 + wv * 2 + j; e < E + j; e += stride8) {
        int ec = (e < E) ? e : (E - 1);
        int s = srcA[ec], d = dstA[ec];
        float2 af = *reinterpret_cast<const float2*>(ea + szt(ec) * FE + (cg & 7) * 2);
        unsigned eap = pk(af.x, af.y);
        uint2 xv = *reinterpret_cast<const uint2*>(xlb + szt(s) * HC + cb);
        uint2 rv = *reinterpret_cast<const uint2*>(xrb + szt(d) * HC + cb);

        float w0 = 0.f, w1 = 0.f, w2 = 0.f, w3 = 0.f;
        #pragma unroll
        for (int kp = 0; kp < 8; ++kp) {
            unsigned a = __shfl(eap, (lane & 32) | kp);
            const unsigned* wp = &sWe[kp * 192 + cg * 6];
            uint2 wa = *reinterpret_cast<const uint2*>(wp);
            uint2 wb = *reinterpret_cast<const uint2*>(wp + 2);
            w0 = dot2(a, wa.x, w0);
            w1 = dot2(a, wa.y, w1);
            w2 = dot2(a, wb.x, w2);
            w3 = dot2(a, wb.y, w3);
        }
        float t0 = bl(xv.x) + bl(rv.x) + w0; t0 = t0 > 0.f ? t0 : NEG * t0;
        float t1 = bh(xv.x) + bh(rv.x) + w1; t1 = t1 > 0.f ? t1 : NEG * t1;
        float t2 = bl(xv.y) + bl(rv.y) + w2; t2 = t2 > 0.f ? t2 : NEG * t2;
        float t3 = bh(xv.y) + bh(rv.y) + w3; t3 = t3 > 0.f ? t3 : NEG * t3;
        float part = attv.x * t0 + attv.y * t1 + attv.z * t2 + attv.w * t3;
        part += __shfl_xor(part, 1);
        part += __shfl_xor(part, 2);
        part += __shfl_xor(part, 4);
        float ex = __expf(part);   // logits are small: no max-subtraction needed
        if (e < E && (cg & 7) == 0) exe[szt(e) * 4 + h] = ex;
    }
}

// ---------------- aggregation (node-parallel) ----------------

__global__ __launch_bounds__(256) void k_aggr(
    const bf16* __restrict__ xlb, const float* __restrict__ exe,
    const float* __restrict__ exself,
    const int2* __restrict__ pairs, const int* __restrict__ row_off,
    const float* __restrict__ bias, float* __restrict__ out,
    float* __restrict__ alpha, float* __restrict__ denom_out, int n, int E)
{
    int lane = threadIdx.x & 63, wv = threadIdx.x >> 6;
    int node = blockIdx.x * 4 + wv;
    if (node >= n) return;
    int j = lane >> 4, cg = lane & 15, cb = cg * 8, h = cg >> 2;
    int beg = row_off[node], end = row_off[node + 1];
    float acc[8];
    #pragma unroll
    for (int i = 0; i < 8; ++i) acc[i] = 0.f;
    float den = 0.f;

    if (beg < end) {
        int last = end - 1;
        int p0 = beg + j; if (p0 > last) p0 = last;
        int2 pr = pairs[p0];
        float ex = exe[szt(pr.y) * 4 + h];
        uint4 xv = *reinterpret_cast<const uint4*>(xlb + szt(pr.x) * HC + cb);
        for (int p = beg; p < end; p += 4) {
            int pn = p + 4 + j; if (pn > last) pn = last;
            int2 prN = pairs[pn];
            float exN = exe[szt(prN.y) * 4 + h];
            uint4 xvN = *reinterpret_cast<const uint4*>(xlb + szt(prN.x) * HC + cb);
            if (p + j < end) {
                den += ex;
                acc[0] += ex * bl(xv.x); acc[1] += ex * bh(xv.x);
                acc[2] += ex * bl(xv.y); acc[3] += ex * bh(xv.y);
                acc[4] += ex * bl(xv.z); acc[5] += ex * bh(xv.z);
                acc[6] += ex * bl(xv.w); acc[7] += ex * bh(xv.w);
            }
            pr = prN; ex = exN; xv = xvN;
        }
    }
    #pragma unroll
    for (int i = 0; i < 8; ++i) {
        acc[i] += __shfl_xor(acc[i], 16);
        acc[i] += __shfl_xor(acc[i], 32);
    }
    den += __shfl_xor(den, 16);
    den += __shfl_xor(den, 32);

    float exs = exself[szt(node) * 4 + h];
    uint4 xs = *reinterpret_cast<const uint4*>(xlb + szt(node) * HC + cb);
    den += exs;
    acc[0] += exs * bl(xs.x); acc[1] += exs * bh(xs.x);
    acc[2] += exs * bl(xs.y); acc[3] += exs * bh(xs.y);
    acc[4] += exs * bl(xs.z); acc[5] += exs * bh(xs.z);
    acc[6] += exs * bl(xs.w); acc[7] += exs * bh(xs.w);

    if (j == 0) {
        float inv = 1.f / den;
        float4 b0 = *reinterpret_cast<const float4*>(bias + cb);
        float4 b1 = *reinterpret_cast<const float4*>(bias + cb + 4);
        float4 o0, o1;
        o0.x = acc[0] * inv + b0.x; o0.x = o0.x > 0.f ? o0.x : 0.f;
        o0.y = acc[1] * inv + b0.y; o0.y = o0.y > 0.f ? o0.y : 0.f;
        o0.z = acc[2] * inv + b0.z; o0.z = o0.z > 0.f ? o0.z : 0.f;
        o0.w = acc[3] * inv + b0.w; o0.w = o0.w > 0.f ? o0.w : 0.f;
        o1.x = acc[4] * inv + b1.x; o1.x = o1.x > 0.f ? o1.x : 0.f;
        o1.y = acc[5] * inv + b1.y; o1.y = o1.y > 0.f ? o1.y : 0.f;
        o1.z = acc[6] * inv + b1.z; o1.z = o1.z > 0.f ? o1.z : 0.f;
        o1.w = acc[7] * inv + b1.w; o1.w = o1.w > 0.f ? o1.w : 0.f;
        *reinterpret_cast<float4*>(out + szt(node) * HC + cb) = o0;
        *reinterpret_cast<float4*>(out + szt(node) * HC + cb + 4) = o1;
        if ((cg & 3) == 0) {
            denom_out[szt(node) * 4 + h] = den;
            alpha[szt(E + node) * 4 + h] = exs * inv;
        }
    }
}

// ---------------- alpha normalization (real edges) ----------------

__global__ void k_norm(const int* __restrict__ dst, const float* __restrict__ denom,
                       const float* __restrict__ exe, float* __restrict__ alpha, int E) {
    int e = blockIdx.x * 256 + threadIdx.x;
    if (e >= E) return;
    int d = dst[e];
    float4 a  = *reinterpret_cast<const float4*>(&exe[szt(e) * 4]);
    float4 dn = *reinterpret_cast<const float4*>(&denom[szt(d) * 4]);
    a.x /= dn.x; a.y /= dn.y; a.z /= dn.z; a.w /= dn.w;
    *reinterpret_cast<float4*>(&alpha[szt(e) * 4]) = a;
}

// ---------------- launch ----------------

extern "C" void kernel_launch(void* const* d_in, const int* in_sizes, int n_in,
                              void* d_out, int out_size, void* d_ws, size_t ws_size,
                              hipStream_t stream) {
    const float* x    = (const float*)d_in[0];
    const int*   ei   = (const int*)d_in[1];
    const float* ea   = (const float*)d_in[2];
    const float* Wl   = (const float*)d_in[3];
    const float* Wr   = (const float*)d_in[4];
    const float* We   = (const float*)d_in[5];
    const float* att  = (const float*)d_in[6];
    const float* bias = (const float*)d_in[7];

    const int n = in_sizes[0] / HC;   // F_IN == 128
    const int E = in_sizes[1] / 2;
    const int* src = ei;
    const int* dst = ei + E;

    char* w = (char*)d_ws;
    size_t off = 0;
    auto alloc = [&](size_t bytes) -> char* {
        char* p = w + off;
        off += (bytes + 255) & ~(size_t)255;
        return p;
    };
    bf16*  xlb     = (bf16*) alloc((size_t)n * HC * 2);
    bf16*  xrb     = (bf16*) alloc((size_t)n * HC * 2);
    float* exe     = (float*)alloc((size_t)E * 4 * 4);
    float* exself  = (float*)alloc((size_t)n * 4 * 4);
    float* denom   = (float*)alloc((size_t)n * 4 * 4);
    int*   cnt     = (int*)  alloc((size_t)n * 4);
    int*   row_off = (int*)  alloc((size_t)(n + 1) * 4);
    int*   cursor  = (int*)  alloc((size_t)n * 4);
    int2*  pairs   = (int2*) alloc((size_t)E * 8);
    s16x8* Wcf     = (s16x8*)alloc((size_t)4096 * 16);
    int    nb      = (n + 4095) / 4096;
    int*   bsum    = (int*)  alloc((size_t)nb * 4);
    (void)ws_size;

    float* out_p   = (float*)d_out;
    float* alpha_p = (float*)d_out + (size_t)n * HC;

    (void)hipMemsetAsync(cnt, 0, (size_t)n * 4, stream);
    k_count<<<(E + 255) / 256, 256, 0, stream>>>(dst, cnt, E);
    k_scan1<<<nb, 1024, 0, stream>>>(cnt, row_off, bsum, n);
    k_scan2<<<1, 64, 0, stream>>>(bsum, nb);
    k_scan3<<<(n + 256) / 256, 256, 0, stream>>>(bsum, row_off, cursor, n, E);
    k_fill <<<(E + 255) / 256, 256, 0, stream>>>(src, dst, cursor, pairs, E);
    k_wprep<<<16, 256, 0, stream>>>(Wl, Wr, Wcf);
    k_gemm2<<<(n + 15) / 16, 256, 0, stream>>>(x, Wcf, xlb, xrb, n);
    k_self <<<(n + 3) / 4, 256, 0, stream>>>(xlb, xrb, ea, pairs, row_off, We, att,
                                             exself, n);
    {
        int nblk = 16384;
        k_logit<<<nblk, 256, 0, stream>>>(xlb, xrb, ea, src, dst, We, att,
                                          exe, E, nblk * 8);
    }
    k_aggr <<<(n + 3) / 4, 256, 0, stream>>>(xlb, exe, exself, pairs, row_off,
                                             bias, out_p, alpha_p, denom, n, E);
    k_norm <<<(E + 255) / 256, 256, 0, stream>>>(dst, denom, exe, alpha_p, E);
}

// Round 10
// 614.553 us; speedup vs baseline: 1.7342x; 1.0068x over previous
//
#include <hip/hip_runtime.h>
#include <hip/hip_bf16.h>

#define HC   128   // H*C
#define FE   16    // edge feature dim
#define NEG  0.2f

using bf16 = __hip_bfloat16;
typedef short s16x8 __attribute__((ext_vector_type(8)));
typedef float f32x4 __attribute__((ext_vector_type(4)));

static __device__ __forceinline__ size_t szt(int a) { return (size_t)a; }
static __device__ __forceinline__ float bl(unsigned u) { return __uint_as_float(u << 16); }
static __device__ __forceinline__ float bh(unsigned u) { return __uint_as_float(u & 0xffff0000u); }
static __device__ __forceinline__ short b16rne(float f) {
    unsigned u = __float_as_uint(f);
    unsigned r = (u + 0x7fffu + ((u >> 16) & 1u)) >> 16;
    return (short)r;
}

// ---------------- CSR build ----------------

__global__ void k_count(const int* __restrict__ dst, int* __restrict__ cnt, int E) {
    int e = blockIdx.x * 256 + threadIdx.x;
    if (e < E) atomicAdd(&cnt[dst[e]], 1);
}

__global__ __launch_bounds__(1024) void k_scan1(const int* __restrict__ cnt,
                                                int* __restrict__ excl,
                                                int* __restrict__ bsum, int n) {
    __shared__ int wsum[16];
    int t = threadIdx.x, lane = t & 63, wv = t >> 6;
    int i = blockIdx.x * 4096 + t * 4;
    int4 c = make_int4(0, 0, 0, 0);
    if (i + 3 < n) c = *reinterpret_cast<const int4*>(&cnt[i]);
    else if (i < n) {
        c.x = cnt[i];
        c.y = (i + 1 < n) ? cnt[i + 1] : 0;
        c.z = (i + 2 < n) ? cnt[i + 2] : 0;
    }
    int tot = c.x + c.y + c.z + c.w;
    int s = tot;
    #pragma unroll
    for (int d = 1; d < 64; d <<= 1) { int u = __shfl_up(s, d); if (lane >= d) s += u; }
    if (lane == 63) wsum[wv] = s;
    __syncthreads();
    if (t < 16) {
        int ws = wsum[t];
        #pragma unroll
        for (int d = 1; d < 16; d <<= 1) { int u = __shfl_up(ws, d); if (t >= d) ws += u; }
        wsum[t] = ws;
    }
    __syncthreads();
    int excl_t = (wv ? wsum[wv - 1] : 0) + (s - tot);
    if (i < n) {
        int4 ro;
        ro.x = excl_t;
        ro.y = ro.x + c.x;
        ro.z = ro.y + c.y;
        ro.w = ro.z + c.z;
        if (i + 3 < n) *reinterpret_cast<int4*>(&excl[i]) = ro;
        else {
            excl[i] = ro.x;
            if (i + 1 < n) excl[i + 1] = ro.y;
            if (i + 2 < n) excl[i + 2] = ro.z;
        }
    }
    if (t == 0) bsum[blockIdx.x] = wsum[15];
}

__global__ void k_scan2(int* __restrict__ bsum, int nb) {
    int t = threadIdx.x;   // 64 threads
    int carry = 0;
    for (int base = 0; base < nb; base += 64) {
        int i = base + t;
        int v = (i < nb) ? bsum[i] : 0;
        int s = v;
        #pragma unroll
        for (int d = 1; d < 64; d <<= 1) { int u = __shfl_up(s, d); if (t >= d) s += u; }
        if (i < nb) bsum[i] = carry + s - v;
        carry += __shfl(s, 63);
    }
}

__global__ void k_scan3(const int* __restrict__ bsum, int* __restrict__ row_off,
                        int* __restrict__ cursor, int n, int E) {
    int i = blockIdx.x * 256 + threadIdx.x;
    if (i < n) {
        int v = row_off[i] + bsum[i >> 12];
        row_off[i] = v;
        cursor[i] = v;
    }
    if (i == n) row_off[n] = E;
}

__global__ void k_fill(const int* __restrict__ src, const int* __restrict__ dst,
                       int* __restrict__ cursor, int2* __restrict__ pairs,
                       int* __restrict__ dst_csr, int E) {
    int e = blockIdx.x * 256 + threadIdx.x;
    if (e < E) {
        int d = dst[e];
        int pos = atomicAdd(&cursor[d], 1);
        pairs[pos] = make_int2(src[e], e);
        dst_csr[pos] = d;
    }
}

// ---------------- weight prep ----------------
// Wcf: [Wl|Wr] B-fragments for k_gemm2 (16x16x32, col=lane&15, k=(lane>>4)*8+j)
__global__ void k_wprep(const float* __restrict__ Wl, const float* __restrict__ Wr,
                        s16x8* __restrict__ Wcf) {
    int idx = blockIdx.x * 256 + threadIdx.x;
    if (idx >= 4096) return;
    int kt = idx >> 10, nt = (idx >> 6) & 15, lane = idx & 63;
    int col = nt * 16 + (lane & 15);
    const float* W = (col < HC) ? Wl : Wr;
    int c = (col < HC) ? col : col - HC;
    s16x8 v;
    #pragma unroll
    for (int j = 0; j < 8; ++j) {
        int k = kt * 32 + (lane >> 4) * 8 + j;
        v[j] = b16rne(W[k * HC + c]);
    }
    Wcf[idx] = v;
}

// Wecf: We^T A-fragments for k_logit (M=ch, K=16 zero-padded to 32)
__global__ void k_wprep2(const float* __restrict__ We, s16x8* __restrict__ Wecf) {
    int idx = blockIdx.x * 256 + threadIdx.x;
    if (idx >= 512) return;
    int lane = idx & 63, g = lane >> 4;
    int ch = (idx >> 6) * 16 + (lane & 15);
    s16x8 v = {0, 0, 0, 0, 0, 0, 0, 0};
    if (g < 2) {
        #pragma unroll
        for (int j = 0; j < 8; ++j)
            v[j] = b16rne(We[(g * 8 + j) * HC + ch]);
    }
    Wecf[idx] = v;
}

// ---------------- projection GEMM via MFMA: [xl|xr] = x @ [Wl|Wr] ----------------

__global__ __launch_bounds__(256) void k_gemm2(const float* __restrict__ x,
                                               const s16x8* __restrict__ Wcf,
                                               bf16* __restrict__ xlb,
                                               bf16* __restrict__ xrb, int n) {
    int t = threadIdx.x, lane = t & 63, w = t >> 6;
    int m0 = blockIdx.x * 16;
    int arow = m0 + (lane & 15);
    if (arow >= n) arow = n - 1;
    const float* xrow = x + szt(arow) * HC + (lane >> 4) * 8;

    f32x4 acc[4];
    #pragma unroll
    for (int nt = 0; nt < 4; ++nt) acc[nt] = (f32x4){0.f, 0.f, 0.f, 0.f};

    #pragma unroll
    for (int kt = 0; kt < 4; ++kt) {
        float4 a0 = *reinterpret_cast<const float4*>(xrow + kt * 32);
        float4 a1 = *reinterpret_cast<const float4*>(xrow + kt * 32 + 4);
        s16x8 af;
        af[0] = b16rne(a0.x); af[1] = b16rne(a0.y);
        af[2] = b16rne(a0.z); af[3] = b16rne(a0.w);
        af[4] = b16rne(a1.x); af[5] = b16rne(a1.y);
        af[6] = b16rne(a1.z); af[7] = b16rne(a1.w);
        #pragma unroll
        for (int nt = 0; nt < 4; ++nt) {
            s16x8 bf = Wcf[(kt * 16 + w * 4 + nt) * 64 + lane];
            acc[nt] = __builtin_amdgcn_mfma_f32_16x16x32_bf16(af, bf, acc[nt], 0, 0, 0);
        }
    }

    bf16* O = (w < 2) ? xlb : xrb;
    int colb = (w & 1) * 64;
    #pragma unroll
    for (int nt = 0; nt < 4; ++nt) {
        int col = colb + nt * 16 + (lane & 15);
        #pragma unroll
        for (int q = 0; q < 4; ++q) {
            int r = m0 + (lane >> 4) * 4 + q;
            if (r < n) O[szt(r) * HC + col] = __float2bfloat16(acc[nt][q]);
        }
    }
}

// ---------------- self-loop: ex_self from mean incoming edge_attr ----------------

__global__ __launch_bounds__(256) void k_self(
    const bf16* __restrict__ xlb, const bf16* __restrict__ xrb,
    const float* __restrict__ ea, const int2* __restrict__ pairs,
    const int* __restrict__ row_off, const float* __restrict__ We,
    const float* __restrict__ att, float* __restrict__ exself, int n)
{
    int lane = threadIdx.x & 63, wv = threadIdx.x >> 6;
    int node = blockIdx.x * 4 + wv;
    if (node >= n) return;
    int beg = row_off[node], end = row_off[node + 1];
    int js = lane >> 4, f = lane & 15;
    float sum = 0.f;
    for (int p = beg + js; p < end; p += 4) {
        int2 pr = pairs[p];
        sum += ea[szt(pr.y) * FE + f];
    }
    sum += __shfl_xor(sum, 16);
    sum += __shfl_xor(sum, 32);
    int deg = end - beg;
    float mean = (deg > 0) ? sum / (float)deg : 0.f;   // lane k holds feature k (replicated)

    int c0 = lane * 2, h = lane >> 4;
    float e0 = 0.f, e1 = 0.f;
    #pragma unroll
    for (int k = 0; k < FE; ++k) {
        float a = __shfl(mean, k);
        float2 w = *reinterpret_cast<const float2*>(We + k * HC + c0);
        e0 += a * w.x; e1 += a * w.y;
    }
    unsigned xu = *reinterpret_cast<const unsigned*>(xlb + szt(node) * HC + c0);
    unsigned ru = *reinterpret_cast<const unsigned*>(xrb + szt(node) * HC + c0);
    float2 av = *reinterpret_cast<const float2*>(att + c0);
    float t0 = bl(xu) + bl(ru) + e0; t0 = t0 > 0.f ? t0 : NEG * t0;
    float t1 = bh(xu) + bh(ru) + e1; t1 = t1 > 0.f ? t1 : NEG * t1;
    float part = av.x * t0 + av.y * t1;
    part += __shfl_xor(part, 1);
    part += __shfl_xor(part, 2);
    part += __shfl_xor(part, 4);
    part += __shfl_xor(part, 8);
    float ex = __expf(part);
    if ((lane & 15) == 0) exself[szt(node) * 4 + h] = ex;
}

// ---------------- edge logits (CSR order, MFMA ee) ----------------
// 16 CSR positions per wave. ee = We^T (M=ch) x ea^T (N=edge) via 8 MFMAs
// (K=16 zero-padded to 32). C layout: edge = lane&15, ch = mt*16+(lane>>4)*4+q.

__global__ __launch_bounds__(256) void k_logit(
    const bf16* __restrict__ xlb, const bf16* __restrict__ xrb,
    const float* __restrict__ ea,
    const int2* __restrict__ pairs, const int* __restrict__ dst_csr,
    const s16x8* __restrict__ Wecf, const float* __restrict__ att,
    float* __restrict__ exe_csr, int E)
{
    __shared__ s16x8 sA[512];
    for (int i = threadIdx.x; i < 512; i += 256) sA[i] = Wecf[i];
    __syncthreads();

    int lane = threadIdx.x & 63, wv = threadIdx.x >> 6;
    int p0 = (blockIdx.x * 4 + wv) * 16;
    if (p0 >= E) return;
    int ei = lane & 15, g = lane >> 4;
    int p = p0 + ei; if (p >= E) p = E - 1;
    int2 pr = pairs[p];
    int d = dst_csr[p];

    // B-frag: ea[eid][k], k = g*8+j (zero for k>=16)
    s16x8 bfrag = {0, 0, 0, 0, 0, 0, 0, 0};
    if (g < 2) {
        const float* ear = ea + szt(pr.y) * FE + g * 8;
        float4 q0 = *reinterpret_cast<const float4*>(ear);
        float4 q1 = *reinterpret_cast<const float4*>(ear + 4);
        bfrag[0] = b16rne(q0.x); bfrag[1] = b16rne(q0.y);
        bfrag[2] = b16rne(q0.z); bfrag[3] = b16rne(q0.w);
        bfrag[4] = b16rne(q1.x); bfrag[5] = b16rne(q1.y);
        bfrag[6] = b16rne(q1.z); bfrag[7] = b16rne(q1.w);
    }

    f32x4 acc[8];
    #pragma unroll
    for (int mt = 0; mt < 8; ++mt) {
        s16x8 afrag = sA[mt * 64 + lane];
        acc[mt] = __builtin_amdgcn_mfma_f32_16x16x32_bf16(
            afrag, bfrag, (f32x4){0.f, 0.f, 0.f, 0.f}, 0, 0, 0);
    }

    const bf16* xrow = xlb + szt(pr.x) * HC;
    const bf16* rrow = xrb + szt(d) * HC;
    float ph0 = 0.f, ph1 = 0.f, ph2 = 0.f, ph3 = 0.f;
    #pragma unroll
    for (int mt = 0; mt < 8; ++mt) {
        int ch0 = mt * 16 + g * 4;
        uint2 xu = *reinterpret_cast<const uint2*>(xrow + ch0);
        uint2 ru = *reinterpret_cast<const uint2*>(rrow + ch0);
        float4 av = *reinterpret_cast<const float4*>(att + ch0);
        float t0 = bl(xu.x) + bl(ru.x) + acc[mt][0]; t0 = t0 > 0.f ? t0 : NEG * t0;
        float t1 = bh(xu.x) + bh(ru.x) + acc[mt][1]; t1 = t1 > 0.f ? t1 : NEG * t1;
        float t2 = bl(xu.y) + bl(ru.y) + acc[mt][2]; t2 = t2 > 0.f ? t2 : NEG * t2;
        float t3 = bh(xu.y) + bh(ru.y) + acc[mt][3]; t3 = t3 > 0.f ? t3 : NEG * t3;
        float pp = av.x * t0 + av.y * t1 + av.z * t2 + av.w * t3;
        if (mt < 2) ph0 += pp; else if (mt < 4) ph1 += pp;
        else if (mt < 6) ph2 += pp; else ph3 += pp;
    }
    ph0 += __shfl_xor(ph0, 16); ph0 += __shfl_xor(ph0, 32);
    ph1 += __shfl_xor(ph1, 16); ph1 += __shfl_xor(ph1, 32);
    ph2 += __shfl_xor(ph2, 16); ph2 += __shfl_xor(ph2, 32);
    ph3 += __shfl_xor(ph3, 16); ph3 += __shfl_xor(ph3, 32);

    if (lane < 16 && p0 + lane < E) {
        float4 o;
        o.x = __expf(ph0); o.y = __expf(ph1);
        o.z = __expf(ph2); o.w = __expf(ph3);   // logits small: no max-subtraction
        *reinterpret_cast<float4*>(exe_csr + szt(p0 + lane) * 4) = o;
    }
}

// ---------------- aggregation (node-parallel) + alpha write ----------------

__global__ __launch_bounds__(256) void k_aggr(
    const bf16* __restrict__ xlb, const float* __restrict__ exe_csr,
    const float* __restrict__ exself,
    const int2* __restrict__ pairs, const int* __restrict__ row_off,
    const float* __restrict__ bias, float* __restrict__ out,
    float* __restrict__ alpha, int n, int E)
{
    int lane = threadIdx.x & 63, wv = threadIdx.x >> 6;
    int node = blockIdx.x * 4 + wv;
    if (node >= n) return;
    int j = lane >> 4, cg = lane & 15, cb = cg * 8, h = cg >> 2;
    int beg = row_off[node], end = row_off[node + 1];
    float acc[8];
    #pragma unroll
    for (int i = 0; i < 8; ++i) acc[i] = 0.f;
    float den = 0.f;

    if (beg < end) {
        int last = end - 1;
        int p0 = beg + j; if (p0 > last) p0 = last;
        int2 pr = pairs[p0];
        float ex = exe_csr[szt(p0) * 4 + h];
        uint4 xv = *reinterpret_cast<const uint4*>(xlb + szt(pr.x) * HC + cb);
        for (int p = beg; p < end; p += 4) {
            int pn = p + 4 + j; if (pn > last) pn = last;
            int2 prN = pairs[pn];
            float exN = exe_csr[szt(pn) * 4 + h];
            uint4 xvN = *reinterpret_cast<const uint4*>(xlb + szt(prN.x) * HC + cb);
            if (p + j < end) {
                den += ex;
                acc[0] += ex * bl(xv.x); acc[1] += ex * bh(xv.x);
                acc[2] += ex * bl(xv.y); acc[3] += ex * bh(xv.y);
                acc[4] += ex * bl(xv.z); acc[5] += ex * bh(xv.z);
                acc[6] += ex * bl(xv.w); acc[7] += ex * bh(xv.w);
            }
            pr = prN; ex = exN; xv = xvN;
        }
    }
    #pragma unroll
    for (int i = 0; i < 8; ++i) {
        acc[i] += __shfl_xor(acc[i], 16);
        acc[i] += __shfl_xor(acc[i], 32);
    }
    den += __shfl_xor(den, 16);
    den += __shfl_xor(den, 32);

    float exs = exself[szt(node) * 4 + h];
    uint4 xs = *reinterpret_cast<const uint4*>(xlb + szt(node) * HC + cb);
    den += exs;
    acc[0] += exs * bl(xs.x); acc[1] += exs * bh(xs.x);
    acc[2] += exs * bl(xs.y); acc[3] += exs * bh(xs.y);
    acc[4] += exs * bl(xs.z); acc[5] += exs * bh(xs.z);
    acc[6] += exs * bl(xs.w); acc[7] += exs * bh(xs.w);

    float inv = 1.f / den;
    if (j == 0) {
        float4 b0 = *reinterpret_cast<const float4*>(bias + cb);
        float4 b1 = *reinterpret_cast<const float4*>(bias + cb + 4);
        float4 o0, o1;
        o0.x = acc[0] * inv + b0.x; o0.x = o0.x > 0.f ? o0.x : 0.f;
        o0.y = acc[1] * inv + b0.y; o0.y = o0.y > 0.f ? o0.y : 0.f;
        o0.z = acc[2] * inv + b0.z; o0.z = o0.z > 0.f ? o0.z : 0.f;
        o0.w = acc[3] * inv + b0.w; o0.w = o0.w > 0.f ? o0.w : 0.f;
        o1.x = acc[4] * inv + b1.x; o1.x = o1.x > 0.f ? o1.x : 0.f;
        o1.y = acc[5] * inv + b1.y; o1.y = o1.y > 0.f ? o1.y : 0.f;
        o1.z = acc[6] * inv + b1.z; o1.z = o1.z > 0.f ? o1.z : 0.f;
        o1.w = acc[7] * inv + b1.w; o1.w = o1.w > 0.f ? o1.w : 0.f;
        *reinterpret_cast<float4*>(out + szt(node) * HC + cb) = o0;
        *reinterpret_cast<float4*>(out + szt(node) * HC + cb + 4) = o1;
        if ((cg & 3) == 0)
            alpha[szt(E + node) * 4 + h] = exs * inv;
    }
    // normalized alpha for real edges: lane handles (pos lane>>2, head lane&3).
    // inv on this lane is for head (lane&15)>>2 -> fetch head (lane&3)'s inv
    // from lane 4*(lane&3) (cg=4h, j=0).  [R9 bug: used mismatched inv]
    float invh = __shfl(inv, 4 * (lane & 3));
    for (int pp = beg + (lane >> 2); pp < end; pp += 16) {
        int eid = pairs[pp].y;
        alpha[szt(eid) * 4 + (lane & 3)] = exe_csr[szt(pp) * 4 + (lane & 3)] * invh;
    }
}

// ---------------- launch ----------------

extern "C" void kernel_launch(void* const* d_in, const int* in_sizes, int n_in,
                              void* d_out, int out_size, void* d_ws, size_t ws_size,
                              hipStream_t stream) {
    const float* x    = (const float*)d_in[0];
    const int*   ei   = (const int*)d_in[1];
    const float* ea   = (const float*)d_in[2];
    const float* Wl   = (const float*)d_in[3];
    const float* Wr   = (const float*)d_in[4];
    const float* We   = (const float*)d_in[5];
    const float* att  = (const float*)d_in[6];
    const float* bias = (const float*)d_in[7];

    const int n = in_sizes[0] / HC;   // F_IN == 128
    const int E = in_sizes[1] / 2;
    const int* src = ei;
    const int* dst = ei + E;

    char* w = (char*)d_ws;
    size_t off = 0;
    auto alloc = [&](size_t bytes) -> char* {
        char* p = w + off;
        off += (bytes + 255) & ~(size_t)255;
        return p;
    };
    bf16*  xlb     = (bf16*) alloc((size_t)n * HC * 2);
    bf16*  xrb     = (bf16*) alloc((size_t)n * HC * 2);
    float* exe_csr = (float*)alloc((size_t)E * 4 * 4);
    float* exself  = (float*)alloc((size_t)n * 4 * 4);
    int*   cnt     = (int*)  alloc((size_t)n * 4);
    int*   row_off = (int*)  alloc((size_t)(n + 1) * 4);
    int*   cursor  = (int*)  alloc((size_t)n * 4);
    int2*  pairs   = (int2*) alloc((size_t)E * 8);
    int*   dst_csr = (int*)  alloc((size_t)E * 4);
    s16x8* Wcf     = (s16x8*)alloc((size_t)4096 * 16);
    s16x8* Wecf    = (s16x8*)alloc((size_t)512 * 16);
    int    nb      = (n + 4095) / 4096;
    int*   bsum    = (int*)  alloc((size_t)nb * 4);
    (void)ws_size;

    float* out_p   = (float*)d_out;
    float* alpha_p = (float*)d_out + (size_t)n * HC;

    (void)hipMemsetAsync(cnt, 0, (size_t)n * 4, stream);
    k_count<<<(E + 255) / 256, 256, 0, stream>>>(dst, cnt, E);
    k_scan1<<<nb, 1024, 0, stream>>>(cnt, row_off, bsum, n);
    k_scan2<<<1, 64, 0, stream>>>(bsum, nb);
    k_scan3<<<(n + 256) / 256, 256, 0, stream>>>(bsum, row_off, cursor, n, E);
    k_fill <<<(E + 255) / 256, 256, 0, stream>>>(src, dst, cursor, pairs, dst_csr, E);
    k_wprep<<<16, 256, 0, stream>>>(Wl, Wr, Wcf);
    k_wprep2<<<2, 256, 0, stream>>>(We, Wecf);
    k_gemm2<<<(n + 15) / 16, 256, 0, stream>>>(x, Wcf, xlb, xrb, n);
    k_self <<<(n + 3) / 4, 256, 0, stream>>>(xlb, xrb, ea, pairs, row_off, We, att,
                                             exself, n);
    k_logit<<<(E + 63) / 64, 256, 0, stream>>>(xlb, xrb, ea, pairs, dst_csr,
                                               Wecf, att, exe_csr, E);
    k_aggr <<<(n + 3) / 4, 256, 0, stream>>>(xlb, exe_csr, exself, pairs, row_off,
                                             bias, out_p, alpha_p, n, E);
}